// Round 2
// baseline (1324.365 us; speedup 1.0000x reference)
//
#include <hip/hip_runtime.h>
#include <math.h>

// ---------------- constants ----------------
constexpr int HDIM = 128;     // hidden width
constexpr int ROWP = 132;     // padded row stride for feature buffers
constexpr float BN_INV = 0.99999500003749980f; // 1/sqrt(1+1e-5)

// monotone float<->uint encoding for atomic max on floats
__device__ __forceinline__ unsigned encf(float f) {
  unsigned u = __float_as_uint(f);
  return (u & 0x80000000u) ? ~u : (u | 0x80000000u);
}
__device__ __forceinline__ float decf(unsigned u) {
  return (u & 0x80000000u) ? __uint_as_float(u ^ 0x80000000u) : __uint_as_float(~u);
}

// ---------------- CSR build ----------------
__global__ void k_hist(const int* __restrict__ ei, int* __restrict__ deg, int E) {
  int e = blockIdx.x * blockDim.x + threadIdx.x;
  if (e < E) atomicAdd(&deg[ei[E + e]], 1);  // dst row
}

__global__ void k_scan_block(const int* __restrict__ deg, int* __restrict__ excl,
                             int* __restrict__ blockSums, int N) {
  __shared__ int s[1024];
  int tid = threadIdx.x;
  int i = blockIdx.x * 1024 + tid;
  int v = (i < N) ? deg[i] : 0;
  s[tid] = v;
  __syncthreads();
  for (int off = 1; off < 1024; off <<= 1) {
    int t = (tid >= off) ? s[tid - off] : 0;
    __syncthreads();
    s[tid] += t;
    __syncthreads();
  }
  if (i < N) excl[i] = s[tid] - v;
  if (tid == 1023) blockSums[blockIdx.x] = s[1023];
}

__global__ void k_scan_sums(int* blockSums, int NB) {
  __shared__ int s[256];
  int tid = threadIdx.x;
  int v = (tid < NB) ? blockSums[tid] : 0;
  s[tid] = v;
  __syncthreads();
  for (int off = 1; off < 256; off <<= 1) {
    int t = (tid >= off) ? s[tid - off] : 0;
    __syncthreads();
    s[tid] += t;
    __syncthreads();
  }
  if (tid < NB) blockSums[tid] = s[tid] - v; // exclusive
}

__global__ void k_scan_add(const int* __restrict__ excl, const int* __restrict__ blockOff,
                           int* __restrict__ rowptr, int N, int E) {
  int i = blockIdx.x * blockDim.x + threadIdx.x;
  if (i < N) rowptr[i] = excl[i] + blockOff[i >> 10];
  if (i == 0) rowptr[N] = E;
}

__global__ void k_fill(const int* __restrict__ ei, const int* __restrict__ rowptr,
                       int* __restrict__ cursor, int* __restrict__ eidx, int E) {
  int e = blockIdx.x * blockDim.x + threadIdx.x;
  if (e >= E) return;
  int s = ei[e];
  int d = ei[E + e];
  int p = atomicAdd(&cursor[d], 1);
  eidx[rowptr[d] + p] = s;
}

// ---------------- feature concat (layer 0) ----------------
// hcat row layout: cols 0..63 = x, 64..65 = pos (layer0 din=66),
// cols 128..129 = pos (so that after GEMM2 overwrites 0..127, [h,pos] is contiguous 130)
__global__ void k_concat0(const float* __restrict__ x, const float* __restrict__ pos,
                          float* __restrict__ hcat, int N) {
  long long idx = (long long)blockIdx.x * blockDim.x + threadIdx.x;
  long long total = (long long)N * ROWP;
  if (idx >= total) return;
  int r = (int)(idx / ROWP);
  int c = (int)(idx - (long long)r * ROWP);
  float v;
  if (c < 64)                 v = x[(size_t)r * 64 + c];
  else if (c < 66)            v = pos[(size_t)r * 2 + (c - 64)];
  else if (c >= 128 && c < 130) v = pos[(size_t)r * 2 + (c - 128)];
  else                        v = 0.0f;
  hcat[idx] = v;
}

// ---------------- neighbor max aggregation:  z = hcat + max_{src->i} hcat[src] ----------------
__global__ __launch_bounds__(256) void k_agg(
    const float* __restrict__ hcat, const int* __restrict__ rowptr,
    const int* __restrict__ eidx, float* __restrict__ z, int din, int N) {
  int wid = (int)((blockIdx.x * 256 + threadIdx.x) >> 6);
  int lane = threadIdx.x & 63;
  if (wid >= N) return;
  int r0 = rowptr[wid], r1 = rowptr[wid + 1];
  const bool has1 = (64 + lane) < din;
  const bool has2 = (128 + lane) < din;
  float m0 = -INFINITY, m1 = -INFINITY, m2 = -INFINITY;
  for (int e = r0; e < r1; ++e) {
    int s = eidx[e];
    const float* row = hcat + (size_t)s * ROWP;
    m0 = fmaxf(m0, row[lane]);
    if (has1) m1 = fmaxf(m1, row[64 + lane]);
    if (has2) m2 = fmaxf(m2, row[128 + lane]);
  }
  if (r0 == r1) { m0 = 0.0f; m1 = 0.0f; m2 = 0.0f; }  // empty neighborhood -> 0
  const float* xr = hcat + (size_t)wid * ROWP;
  float* zr = z + (size_t)wid * ROWP;
  zr[lane] = xr[lane] + m0;
  if (has1) zr[64 + lane] = xr[64 + lane] + m1;
  if (has2) zr[128 + lane] = xr[128 + lane] + m2;
}

// ---------------- GEMM + bias + BN(eval) + ReLU ----------------
// out[n][c] = relu( (sum_k A[n][k]*W[k][c] + b[c]) * (g[c]*BN_INV) + be[c] )
// A: [N][lda] (first K cols valid), W: [K][128], out: [N][ldo] (writes cols 0..127)
__global__ __launch_bounds__(256) void k_gemm(
    const float* __restrict__ A, int lda, int K,
    const float* __restrict__ W, const float* __restrict__ bias,
    const float* __restrict__ gamma, const float* __restrict__ beta,
    float* __restrict__ out, int ldo, int N) {
  __shared__ float sA[64 * ROWP];
  const int tid = threadIdx.x;
  const int row0 = blockIdx.x * 64;

  // stage 64 rows of A into LDS (coalesced: one row per iteration)
  for (int r = 0; r < 64; ++r) {
    if (tid < K) {
      int gr = row0 + r;
      sA[r * ROWP + tid] = (gr < N) ? A[(size_t)gr * lda + tid] : 0.0f;
    }
  }
  __syncthreads();

  const int col4 = (tid & 31) * 4;    // 4 consecutive output cols
  const int rbase = (tid >> 5) * 8;   // 8 rows
  float4 acc[8];
#pragma unroll
  for (int r = 0; r < 8; ++r) acc[r] = make_float4(0.f, 0.f, 0.f, 0.f);

  const int K4 = K & ~3;
  for (int k = 0; k < K4; k += 4) {
    float4 w0 = *(const float4*)(W + (size_t)(k + 0) * HDIM + col4);
    float4 w1 = *(const float4*)(W + (size_t)(k + 1) * HDIM + col4);
    float4 w2 = *(const float4*)(W + (size_t)(k + 2) * HDIM + col4);
    float4 w3 = *(const float4*)(W + (size_t)(k + 3) * HDIM + col4);
#pragma unroll
    for (int r = 0; r < 8; ++r) {
      float4 a = *(const float4*)(&sA[(rbase + r) * ROWP + k]);
      acc[r].x = fmaf(a.x, w0.x, acc[r].x);
      acc[r].y = fmaf(a.x, w0.y, acc[r].y);
      acc[r].z = fmaf(a.x, w0.z, acc[r].z);
      acc[r].w = fmaf(a.x, w0.w, acc[r].w);
      acc[r].x = fmaf(a.y, w1.x, acc[r].x);
      acc[r].y = fmaf(a.y, w1.y, acc[r].y);
      acc[r].z = fmaf(a.y, w1.z, acc[r].z);
      acc[r].w = fmaf(a.y, w1.w, acc[r].w);
      acc[r].x = fmaf(a.z, w2.x, acc[r].x);
      acc[r].y = fmaf(a.z, w2.y, acc[r].y);
      acc[r].z = fmaf(a.z, w2.z, acc[r].z);
      acc[r].w = fmaf(a.z, w2.w, acc[r].w);
      acc[r].x = fmaf(a.w, w3.x, acc[r].x);
      acc[r].y = fmaf(a.w, w3.y, acc[r].y);
      acc[r].z = fmaf(a.w, w3.z, acc[r].z);
      acc[r].w = fmaf(a.w, w3.w, acc[r].w);
    }
  }
  for (int k = K4; k < K; ++k) {
    float4 w0 = *(const float4*)(W + (size_t)k * HDIM + col4);
#pragma unroll
    for (int r = 0; r < 8; ++r) {
      float a = sA[(rbase + r) * ROWP + k];
      acc[r].x = fmaf(a, w0.x, acc[r].x);
      acc[r].y = fmaf(a, w0.y, acc[r].y);
      acc[r].z = fmaf(a, w0.z, acc[r].z);
      acc[r].w = fmaf(a, w0.w, acc[r].w);
    }
  }

  float4 bb = *(const float4*)(bias + col4);
  float4 gg = *(const float4*)(gamma + col4);
  float4 ee = *(const float4*)(beta + col4);
  float s0 = gg.x * BN_INV, s1 = gg.y * BN_INV, s2 = gg.z * BN_INV, s3 = gg.w * BN_INV;

#pragma unroll
  for (int r = 0; r < 8; ++r) {
    int gr = row0 + rbase + r;
    if (gr >= N) continue;
    float4 o;
    o.x = fmaxf(fmaf(acc[r].x + bb.x, s0, ee.x), 0.0f);
    o.y = fmaxf(fmaf(acc[r].y + bb.y, s1, ee.y), 0.0f);
    o.z = fmaxf(fmaf(acc[r].z + bb.z, s2, ee.z), 0.0f);
    o.w = fmaxf(fmaf(acc[r].w + bb.w, s3, ee.w), 0.0f);
    *(float4*)(out + (size_t)gr * ldo + col4) = o;
  }
}

// ---------------- global max pool (batch sorted) ----------------
__global__ void k_pool_init(unsigned* pooled, int GH) {
  int i = blockIdx.x * blockDim.x + threadIdx.x;
  if (i < GH) pooled[i] = 0x007FFFFFu;  // enc(-inf)
}

__global__ __launch_bounds__(128) void k_pool(
    const float* __restrict__ hcat, const int* __restrict__ batch,
    unsigned* __restrict__ pooled, int N) {
  int base = blockIdx.x * 128;
  int c = threadIdx.x;
  int end = min(base + 128, N);
  int curg = -1;
  float m = -INFINITY;
  for (int i = base; i < end; ++i) {
    int g = batch[i];
    if (g != curg) {
      if (curg >= 0) atomicMax(&pooled[curg * HDIM + c], encf(m));
      curg = g;
      m = -INFINITY;
    }
    m = fmaxf(m, hcat[(size_t)i * ROWP + c]);
  }
  if (curg >= 0) atomicMax(&pooled[curg * HDIM + c], encf(m));
}

// ---------------- final linear [G,128] @ [128,2] ----------------
__global__ __launch_bounds__(64) void k_final(
    const unsigned* __restrict__ pooled, const float* __restrict__ wlin,
    const float* __restrict__ blin, float* __restrict__ out) {
  int g = blockIdx.x;
  int lane = threadIdx.x;
  float v0 = decf(pooled[g * HDIM + lane]);
  float v1 = decf(pooled[g * HDIM + 64 + lane]);
  if (v0 == -INFINITY) v0 = 0.0f;  // empty graph -> 0
  if (v1 == -INFINITY) v1 = 0.0f;
  float p0 = v0 * wlin[lane * 2 + 0] + v1 * wlin[(64 + lane) * 2 + 0];
  float p1 = v0 * wlin[lane * 2 + 1] + v1 * wlin[(64 + lane) * 2 + 1];
  for (int off = 32; off > 0; off >>= 1) {
    p0 += __shfl_down(p0, off);
    p1 += __shfl_down(p1, off);
  }
  if (lane == 0) {
    out[g * 2 + 0] = p0 + blin[0];
    out[g * 2 + 1] = p1 + blin[1];
  }
}

// ---------------- host launcher ----------------
static inline size_t ws_align(size_t x) { return (x + 511) & ~(size_t)511; }

extern "C" void kernel_launch(void* const* d_in, const int* in_sizes, int n_in,
                              void* d_out, int out_size, void* d_ws, size_t ws_size,
                              hipStream_t stream) {
  const float* x    = (const float*)d_in[0];
  const float* pos  = (const float*)d_in[1];
  const int*   ei   = (const int*)d_in[2];
  const int*   batch = (const int*)d_in[3];
  const float* wlin = (const float*)d_in[28];
  const float* blin = (const float*)d_in[29];

  const int N = in_sizes[3];          // batch has N elements
  const int E = in_sizes[2] / 2;
  const int G = out_size / 2;

  // workspace layout
  char* w = (char*)d_ws;
  size_t off = 0;
  auto take = [&](size_t bytes) { void* p = w + off; off += ws_align(bytes); return p; };
  int*      deg     = (int*)take((size_t)N * 4);
  int*      cursor  = (int*)take((size_t)N * 4);
  int*      rowptr  = (int*)take((size_t)(N + 1) * 4);
  int*      excl    = (int*)take((size_t)N * 4);
  int*      bsums   = (int*)take(4096);
  int*      eidx    = (int*)take((size_t)E * 4);
  float*    hcat    = (float*)take((size_t)N * ROWP * 4);
  float*    z       = (float*)take((size_t)N * ROWP * 4);
  float*    h1      = (float*)take((size_t)N * HDIM * 4);
  unsigned* pooled  = (unsigned*)take((size_t)G * HDIM * 4);
  (void)ws_size;

  const int NB = (N + 1023) / 1024;

  // ---- build CSR by dst ----
  hipMemsetAsync(deg, 0, (size_t)N * 4, stream);
  k_hist<<<(E + 255) / 256, 256, 0, stream>>>(ei, deg, E);
  k_scan_block<<<NB, 1024, 0, stream>>>(deg, excl, bsums, N);
  k_scan_sums<<<1, 256, 0, stream>>>(bsums, NB);
  k_scan_add<<<(N + 255) / 256, 256, 0, stream>>>(excl, bsums, rowptr, N, E);
  hipMemsetAsync(cursor, 0, (size_t)N * 4, stream);
  k_fill<<<(E + 255) / 256, 256, 0, stream>>>(ei, rowptr, cursor, eidx, E);

  // ---- layer 0 input ----
  {
    long long total = (long long)N * ROWP;
    k_concat0<<<(int)((total + 255) / 256), 256, 0, stream>>>(x, pos, hcat, N);
  }

  const int din[3] = {66, 130, 130};
  const int aggBlocks = (N + 3) / 4;   // 4 waves (nodes) per 256-thread block
  const int gemmBlocks = (N + 63) / 64;

  for (int l = 0; l < 3; ++l) {
    const float* w1 = (const float*)d_in[4 + l * 8 + 0];
    const float* b1 = (const float*)d_in[4 + l * 8 + 1];
    const float* g1 = (const float*)d_in[4 + l * 8 + 2];
    const float* e1 = (const float*)d_in[4 + l * 8 + 3];
    const float* w2 = (const float*)d_in[4 + l * 8 + 4];
    const float* b2 = (const float*)d_in[4 + l * 8 + 5];
    const float* g2 = (const float*)d_in[4 + l * 8 + 6];
    const float* e2 = (const float*)d_in[4 + l * 8 + 7];

    k_agg<<<aggBlocks, 256, 0, stream>>>(hcat, rowptr, eidx, z, din[l], N);
    k_gemm<<<gemmBlocks, 256, 0, stream>>>(z, ROWP, din[l], w1, b1, g1, e1, h1, HDIM, N);
    // GEMM2 writes h back into hcat cols 0..127; pos persists at cols 128..129
    k_gemm<<<gemmBlocks, 256, 0, stream>>>(h1, HDIM, HDIM, w2, b2, g2, e2, hcat, ROWP, N);
  }

  // ---- pool + final linear ----
  k_pool_init<<<(G * HDIM + 255) / 256, 256, 0, stream>>>(pooled, G * HDIM);
  k_pool<<<(N + 127) / 128, 128, 0, stream>>>(hcat, batch, pooled, N);
  k_final<<<G, 64, 0, stream>>>(pooled, wlin, blin, (float*)d_out);
}

// Round 3
// 924.337 us; speedup vs baseline: 1.4328x; 1.4328x over previous
//
#include <hip/hip_runtime.h>
#include <math.h>

// ---------------- constants ----------------
constexpr int HDIM = 128;     // hidden width
constexpr int ROWP = 132;     // padded row stride for feature buffers (132*4=528B, 16B aligned)
constexpr float BN_INV = 0.99999500003749980f; // 1/sqrt(1+1e-5)

// monotone float<->uint encoding for atomic max on floats
__device__ __forceinline__ unsigned encf(float f) {
  unsigned u = __float_as_uint(f);
  return (u & 0x80000000u) ? ~u : (u | 0x80000000u);
}
__device__ __forceinline__ float decf(unsigned u) {
  return (u & 0x80000000u) ? __uint_as_float(u ^ 0x80000000u) : __uint_as_float(~u);
}

// ---------------- CSR build ----------------
__global__ void k_hist(const int* __restrict__ ei, int* __restrict__ deg, int E) {
  int e = blockIdx.x * blockDim.x + threadIdx.x;
  if (e < E) atomicAdd(&deg[ei[E + e]], 1);  // dst row
}

__global__ void k_scan_block(const int* __restrict__ deg, int* __restrict__ excl,
                             int* __restrict__ blockSums, int N) {
  __shared__ int s[1024];
  int tid = threadIdx.x;
  int i = blockIdx.x * 1024 + tid;
  int v = (i < N) ? deg[i] : 0;
  s[tid] = v;
  __syncthreads();
  for (int off = 1; off < 1024; off <<= 1) {
    int t = (tid >= off) ? s[tid - off] : 0;
    __syncthreads();
    s[tid] += t;
    __syncthreads();
  }
  if (i < N) excl[i] = s[tid] - v;
  if (tid == 1023) blockSums[blockIdx.x] = s[1023];
}

__global__ void k_scan_sums(int* blockSums, int NB) {
  __shared__ int s[256];
  int tid = threadIdx.x;
  int v = (tid < NB) ? blockSums[tid] : 0;
  s[tid] = v;
  __syncthreads();
  for (int off = 1; off < 256; off <<= 1) {
    int t = (tid >= off) ? s[tid - off] : 0;
    __syncthreads();
    s[tid] += t;
    __syncthreads();
  }
  if (tid < NB) blockSums[tid] = s[tid] - v; // exclusive
}

__global__ void k_scan_add(const int* __restrict__ excl, const int* __restrict__ blockOff,
                           int* __restrict__ rowptr, int N, int E) {
  int i = blockIdx.x * blockDim.x + threadIdx.x;
  if (i < N) rowptr[i] = excl[i] + blockOff[i >> 10];
  if (i == 0) rowptr[N] = E;
}

__global__ void k_fill(const int* __restrict__ ei, const int* __restrict__ rowptr,
                       int* __restrict__ cursor, int* __restrict__ eidx, int E) {
  int e = blockIdx.x * blockDim.x + threadIdx.x;
  if (e >= E) return;
  int s = ei[e];
  int d = ei[E + e];
  int p = atomicAdd(&cursor[d], 1);
  eidx[rowptr[d] + p] = s;
}

// ---------------- feature concat (layer 0) ----------------
// hcat row: cols 0..63 = x, 64..65 = pos (layer0 din=66), 66..127 = 0,
// cols 128..129 = pos (so after GEMM2 overwrites 0..127, [h,pos] is contiguous 130), 130..131 = 0
__global__ void k_concat0(const float* __restrict__ x, const float* __restrict__ pos,
                          float* __restrict__ hcat, int N) {
  long long idx = (long long)blockIdx.x * blockDim.x + threadIdx.x;
  long long total = (long long)N * ROWP;
  if (idx >= total) return;
  int r = (int)(idx / ROWP);
  int c = (int)(idx - (long long)r * ROWP);
  float v;
  if (c < 64)                   v = x[(size_t)r * 64 + c];
  else if (c < 66)              v = pos[(size_t)r * 2 + (c - 64)];
  else if (c >= 128 && c < 130) v = pos[(size_t)r * 2 + (c - 128)];
  else                          v = 0.0f;
  hcat[idx] = v;
}

// ---------------- neighbor max aggregation:  z = hcat + max_{src->i} hcat[src] ----------------
// one wave per node; lane handles float2 at col 2*lane; lane 0 also cols 128..129 when din=130.
// 4x edge unroll -> 4 independent gathers in flight (latency hiding).
__global__ __launch_bounds__(256) void k_agg(
    const float* __restrict__ hcat, const int* __restrict__ rowptr,
    const int* __restrict__ eidx, float* __restrict__ z, int din, int N) {
  int wid = (int)((blockIdx.x * 256 + threadIdx.x) >> 6);
  int lane = threadIdx.x & 63;
  if (wid >= N) return;
  int r0 = rowptr[wid], r1 = rowptr[wid + 1];
  const int c2 = 2 * lane;
  const bool act = c2 < din;                 // din=66 -> lanes 0..32, din=130 -> all
  const bool tail = (din > 128) && (lane == 0);

  float2 m = make_float2(-INFINITY, -INFINITY);
  float2 mt = make_float2(-INFINITY, -INFINITY);

  int e = r0;
  for (; e + 4 <= r1; e += 4) {
    int s0 = eidx[e + 0], s1 = eidx[e + 1], s2 = eidx[e + 2], s3 = eidx[e + 3];
    if (act) {
      float2 v0 = *(const float2*)(hcat + (size_t)s0 * ROWP + c2);
      float2 v1 = *(const float2*)(hcat + (size_t)s1 * ROWP + c2);
      float2 v2 = *(const float2*)(hcat + (size_t)s2 * ROWP + c2);
      float2 v3 = *(const float2*)(hcat + (size_t)s3 * ROWP + c2);
      m.x = fmaxf(m.x, fmaxf(fmaxf(v0.x, v1.x), fmaxf(v2.x, v3.x)));
      m.y = fmaxf(m.y, fmaxf(fmaxf(v0.y, v1.y), fmaxf(v2.y, v3.y)));
    }
    if (tail) {
      float2 t0 = *(const float2*)(hcat + (size_t)s0 * ROWP + 128);
      float2 t1 = *(const float2*)(hcat + (size_t)s1 * ROWP + 128);
      float2 t2 = *(const float2*)(hcat + (size_t)s2 * ROWP + 128);
      float2 t3 = *(const float2*)(hcat + (size_t)s3 * ROWP + 128);
      mt.x = fmaxf(mt.x, fmaxf(fmaxf(t0.x, t1.x), fmaxf(t2.x, t3.x)));
      mt.y = fmaxf(mt.y, fmaxf(fmaxf(t0.y, t1.y), fmaxf(t2.y, t3.y)));
    }
  }
  for (; e < r1; ++e) {
    int s = eidx[e];
    if (act) {
      float2 v = *(const float2*)(hcat + (size_t)s * ROWP + c2);
      m.x = fmaxf(m.x, v.x);
      m.y = fmaxf(m.y, v.y);
    }
    if (tail) {
      float2 t = *(const float2*)(hcat + (size_t)s * ROWP + 128);
      mt.x = fmaxf(mt.x, t.x);
      mt.y = fmaxf(mt.y, t.y);
    }
  }

  const bool none = (r0 == r1);   // empty neighborhood -> agg = 0
  if (act) {
    float2 a = *(const float2*)(hcat + (size_t)wid * ROWP + c2);
    float2 o;
    o.x = a.x + (none ? 0.0f : m.x);
    o.y = a.y + (none ? 0.0f : m.y);
    *(float2*)(z + (size_t)wid * ROWP + c2) = o;
  }
  if (tail) {
    float2 a = *(const float2*)(hcat + (size_t)wid * ROWP + 128);
    float2 o;
    o.x = a.x + (none ? 0.0f : mt.x);
    o.y = a.y + (none ? 0.0f : mt.y);
    *(float2*)(z + (size_t)wid * ROWP + 128) = o;
  }
}

// ---------------- fused MLP: relu(BN(relu(BN(A@W1+b1))@W2+b2)) ----------------
// A: [N][ROWP] (first K1 cols valid), W1: [K1][128], W2: [128][128], out: [N][ldo] cols 0..127.
// One LDS tile (64 x ROWP) holds A, then is overwritten with h1 for GEMM2.
__global__ __launch_bounds__(256) void k_mlp(
    const float* __restrict__ A, int K1,
    const float* __restrict__ W1, const float* __restrict__ b1,
    const float* __restrict__ g1, const float* __restrict__ e1,
    const float* __restrict__ W2, const float* __restrict__ b2,
    const float* __restrict__ g2, const float* __restrict__ e2,
    float* __restrict__ out, int ldo, int N) {
  __shared__ float sA[64 * ROWP];
  const int tid = threadIdx.x;
  const int row0 = blockIdx.x * 64;

  // cooperative float4 staging of ceil(K1/4) vec4s per row
  const int jmax = (K1 + 3) >> 2;            // 17 (K1=66) or 33 (K1=130)
  for (int idx = tid; idx < 64 * jmax; idx += 256) {
    int r = idx / jmax;
    int j = idx - r * jmax;
    int gr = row0 + r;
    float4 v = make_float4(0.f, 0.f, 0.f, 0.f);
    if (gr < N) v = *(const float4*)(A + (size_t)gr * ROWP + j * 4);
    *(float4*)(&sA[r * ROWP + j * 4]) = v;
  }
  __syncthreads();

  const int col4 = (tid & 31) * 4;    // 4 consecutive output cols
  const int rbase = (tid >> 5) * 8;   // 8 rows

  float4 acc[8];
  // ---- GEMM1 over K1 ----
#pragma unroll
  for (int r = 0; r < 8; ++r) acc[r] = make_float4(0.f, 0.f, 0.f, 0.f);
  {
    const int K4 = K1 & ~3;
    for (int k = 0; k < K4; k += 4) {
      float4 w0 = *(const float4*)(W1 + (size_t)(k + 0) * HDIM + col4);
      float4 w1 = *(const float4*)(W1 + (size_t)(k + 1) * HDIM + col4);
      float4 w2 = *(const float4*)(W1 + (size_t)(k + 2) * HDIM + col4);
      float4 w3 = *(const float4*)(W1 + (size_t)(k + 3) * HDIM + col4);
#pragma unroll
      for (int r = 0; r < 8; ++r) {
        float4 a = *(const float4*)(&sA[(rbase + r) * ROWP + k]);
        acc[r].x = fmaf(a.x, w0.x, acc[r].x);
        acc[r].y = fmaf(a.x, w0.y, acc[r].y);
        acc[r].z = fmaf(a.x, w0.z, acc[r].z);
        acc[r].w = fmaf(a.x, w0.w, acc[r].w);
        acc[r].x = fmaf(a.y, w1.x, acc[r].x);
        acc[r].y = fmaf(a.y, w1.y, acc[r].y);
        acc[r].z = fmaf(a.y, w1.z, acc[r].z);
        acc[r].w = fmaf(a.y, w1.w, acc[r].w);
        acc[r].x = fmaf(a.z, w2.x, acc[r].x);
        acc[r].y = fmaf(a.z, w2.y, acc[r].y);
        acc[r].z = fmaf(a.z, w2.z, acc[r].z);
        acc[r].w = fmaf(a.z, w2.w, acc[r].w);
        acc[r].x = fmaf(a.w, w3.x, acc[r].x);
        acc[r].y = fmaf(a.w, w3.y, acc[r].y);
        acc[r].z = fmaf(a.w, w3.z, acc[r].z);
        acc[r].w = fmaf(a.w, w3.w, acc[r].w);
      }
    }
    for (int k = K4; k < K1; ++k) {
      float4 w0 = *(const float4*)(W1 + (size_t)k * HDIM + col4);
#pragma unroll
      for (int r = 0; r < 8; ++r) {
        float a = sA[(rbase + r) * ROWP + k];
        acc[r].x = fmaf(a, w0.x, acc[r].x);
        acc[r].y = fmaf(a, w0.y, acc[r].y);
        acc[r].z = fmaf(a, w0.z, acc[r].z);
        acc[r].w = fmaf(a, w0.w, acc[r].w);
      }
    }
  }

  // epilogue 1 -> write h1 back into the SAME LDS tile
  {
    float4 bb = *(const float4*)(b1 + col4);
    float4 gg = *(const float4*)(g1 + col4);
    float4 ee = *(const float4*)(e1 + col4);
    float s0 = gg.x * BN_INV, s1 = gg.y * BN_INV, s2 = gg.z * BN_INV, s3 = gg.w * BN_INV;
    __syncthreads();   // everyone done READING sA as A
#pragma unroll
    for (int r = 0; r < 8; ++r) {
      float4 o;
      o.x = fmaxf(fmaf(acc[r].x + bb.x, s0, ee.x), 0.0f);
      o.y = fmaxf(fmaf(acc[r].y + bb.y, s1, ee.y), 0.0f);
      o.z = fmaxf(fmaf(acc[r].z + bb.z, s2, ee.z), 0.0f);
      o.w = fmaxf(fmaf(acc[r].w + bb.w, s3, ee.w), 0.0f);
      *(float4*)(&sA[(rbase + r) * ROWP + col4]) = o;
    }
    __syncthreads();   // h1 tile visible to all
  }

  // ---- GEMM2 over K=128 ----
#pragma unroll
  for (int r = 0; r < 8; ++r) acc[r] = make_float4(0.f, 0.f, 0.f, 0.f);
  for (int k = 0; k < HDIM; k += 4) {
    float4 w0 = *(const float4*)(W2 + (size_t)(k + 0) * HDIM + col4);
    float4 w1 = *(const float4*)(W2 + (size_t)(k + 1) * HDIM + col4);
    float4 w2 = *(const float4*)(W2 + (size_t)(k + 2) * HDIM + col4);
    float4 w3 = *(const float4*)(W2 + (size_t)(k + 3) * HDIM + col4);
#pragma unroll
    for (int r = 0; r < 8; ++r) {
      float4 a = *(const float4*)(&sA[(rbase + r) * ROWP + k]);
      acc[r].x = fmaf(a.x, w0.x, acc[r].x);
      acc[r].y = fmaf(a.x, w0.y, acc[r].y);
      acc[r].z = fmaf(a.x, w0.z, acc[r].z);
      acc[r].w = fmaf(a.x, w0.w, acc[r].w);
      acc[r].x = fmaf(a.y, w1.x, acc[r].x);
      acc[r].y = fmaf(a.y, w1.y, acc[r].y);
      acc[r].z = fmaf(a.y, w1.z, acc[r].z);
      acc[r].w = fmaf(a.y, w1.w, acc[r].w);
      acc[r].x = fmaf(a.z, w2.x, acc[r].x);
      acc[r].y = fmaf(a.z, w2.y, acc[r].y);
      acc[r].z = fmaf(a.z, w2.z, acc[r].z);
      acc[r].w = fmaf(a.z, w2.w, acc[r].w);
      acc[r].x = fmaf(a.w, w3.x, acc[r].x);
      acc[r].y = fmaf(a.w, w3.y, acc[r].y);
      acc[r].z = fmaf(a.w, w3.z, acc[r].z);
      acc[r].w = fmaf(a.w, w3.w, acc[r].w);
    }
  }

  // epilogue 2 -> global
  {
    float4 bb = *(const float4*)(b2 + col4);
    float4 gg = *(const float4*)(g2 + col4);
    float4 ee = *(const float4*)(e2 + col4);
    float s0 = gg.x * BN_INV, s1 = gg.y * BN_INV, s2 = gg.z * BN_INV, s3 = gg.w * BN_INV;
#pragma unroll
    for (int r = 0; r < 8; ++r) {
      int gr = row0 + rbase + r;
      if (gr >= N) continue;
      float4 o;
      o.x = fmaxf(fmaf(acc[r].x + bb.x, s0, ee.x), 0.0f);
      o.y = fmaxf(fmaf(acc[r].y + bb.y, s1, ee.y), 0.0f);
      o.z = fmaxf(fmaf(acc[r].z + bb.z, s2, ee.z), 0.0f);
      o.w = fmaxf(fmaf(acc[r].w + bb.w, s3, ee.w), 0.0f);
      *(float4*)(out + (size_t)gr * ldo + col4) = o;
    }
  }
}

// ---------------- global max pool (batch sorted) ----------------
__global__ void k_pool_init(unsigned* pooled, int GH) {
  int i = blockIdx.x * blockDim.x + threadIdx.x;
  if (i < GH) pooled[i] = 0x007FFFFFu;  // enc(-inf)
}

__global__ __launch_bounds__(128) void k_pool(
    const float* __restrict__ hcat, const int* __restrict__ batch,
    unsigned* __restrict__ pooled, int N) {
  int base = blockIdx.x * 128;
  int c = threadIdx.x;
  int end = min(base + 128, N);
  int curg = -1;
  float m = -INFINITY;
  for (int i = base; i < end; ++i) {
    int g = batch[i];
    if (g != curg) {
      if (curg >= 0) atomicMax(&pooled[curg * HDIM + c], encf(m));
      curg = g;
      m = -INFINITY;
    }
    m = fmaxf(m, hcat[(size_t)i * ROWP + c]);
  }
  if (curg >= 0) atomicMax(&pooled[curg * HDIM + c], encf(m));
}

// ---------------- final linear [G,128] @ [128,2] ----------------
__global__ __launch_bounds__(64) void k_final(
    const unsigned* __restrict__ pooled, const float* __restrict__ wlin,
    const float* __restrict__ blin, float* __restrict__ out) {
  int g = blockIdx.x;
  int lane = threadIdx.x;
  float v0 = decf(pooled[g * HDIM + lane]);
  float v1 = decf(pooled[g * HDIM + 64 + lane]);
  if (v0 == -INFINITY) v0 = 0.0f;  // empty graph -> 0
  if (v1 == -INFINITY) v1 = 0.0f;
  float p0 = v0 * wlin[lane * 2 + 0] + v1 * wlin[(64 + lane) * 2 + 0];
  float p1 = v0 * wlin[lane * 2 + 1] + v1 * wlin[(64 + lane) * 2 + 1];
  for (int off = 32; off > 0; off >>= 1) {
    p0 += __shfl_down(p0, off);
    p1 += __shfl_down(p1, off);
  }
  if (lane == 0) {
    out[g * 2 + 0] = p0 + blin[0];
    out[g * 2 + 1] = p1 + blin[1];
  }
}

// ---------------- host launcher ----------------
static inline size_t ws_align(size_t x) { return (x + 511) & ~(size_t)511; }

extern "C" void kernel_launch(void* const* d_in, const int* in_sizes, int n_in,
                              void* d_out, int out_size, void* d_ws, size_t ws_size,
                              hipStream_t stream) {
  const float* x     = (const float*)d_in[0];
  const float* pos   = (const float*)d_in[1];
  const int*   ei    = (const int*)d_in[2];
  const int*   batch = (const int*)d_in[3];
  const float* wlin  = (const float*)d_in[28];
  const float* blin  = (const float*)d_in[29];

  const int N = in_sizes[3];          // batch has N elements
  const int E = in_sizes[2] / 2;
  const int G = out_size / 2;

  // workspace layout
  char* w = (char*)d_ws;
  size_t off = 0;
  auto take = [&](size_t bytes) { void* p = w + off; off += ws_align(bytes); return p; };
  int*      deg    = (int*)take((size_t)N * 4);
  int*      cursor = (int*)take((size_t)N * 4);
  int*      rowptr = (int*)take((size_t)(N + 1) * 4);
  int*      excl   = (int*)take((size_t)N * 4);
  int*      bsums  = (int*)take(4096);
  int*      eidx   = (int*)take((size_t)E * 4);
  float*    hcat   = (float*)take((size_t)N * ROWP * 4);
  float*    z      = (float*)take((size_t)N * ROWP * 4);
  unsigned* pooled = (unsigned*)take((size_t)G * HDIM * 4);
  (void)ws_size;

  const int NB = (N + 1023) / 1024;

  // ---- build CSR by dst ----
  hipMemsetAsync(deg, 0, (size_t)N * 4, stream);
  k_hist<<<(E + 255) / 256, 256, 0, stream>>>(ei, deg, E);
  k_scan_block<<<NB, 1024, 0, stream>>>(deg, excl, bsums, N);
  k_scan_sums<<<1, 256, 0, stream>>>(bsums, NB);
  k_scan_add<<<(N + 255) / 256, 256, 0, stream>>>(excl, bsums, rowptr, N, E);
  hipMemsetAsync(cursor, 0, (size_t)N * 4, stream);
  k_fill<<<(E + 255) / 256, 256, 0, stream>>>(ei, rowptr, cursor, eidx, E);

  // ---- layer 0 input ----
  {
    long long total = (long long)N * ROWP;
    k_concat0<<<(int)((total + 255) / 256), 256, 0, stream>>>(x, pos, hcat, N);
  }

  const int din[3] = {66, 130, 130};
  const int aggBlocks = (N + 3) / 4;   // 4 waves (nodes) per 256-thread block
  const int gemmBlocks = (N + 63) / 64;

  for (int l = 0; l < 3; ++l) {
    const float* w1 = (const float*)d_in[4 + l * 8 + 0];
    const float* b1 = (const float*)d_in[4 + l * 8 + 1];
    const float* g1 = (const float*)d_in[4 + l * 8 + 2];
    const float* e1 = (const float*)d_in[4 + l * 8 + 3];
    const float* w2 = (const float*)d_in[4 + l * 8 + 4];
    const float* b2 = (const float*)d_in[4 + l * 8 + 5];
    const float* g2 = (const float*)d_in[4 + l * 8 + 6];
    const float* e2 = (const float*)d_in[4 + l * 8 + 7];

    k_agg<<<aggBlocks, 256, 0, stream>>>(hcat, rowptr, eidx, z, din[l], N);
    // fused MLP: GEMM1(+BN+ReLU) -> LDS -> GEMM2(+BN+ReLU) -> hcat cols 0..127
    k_mlp<<<gemmBlocks, 256, 0, stream>>>(z, din[l], w1, b1, g1, e1, w2, b2, g2, e2,
                                          hcat, ROWP, N);
  }

  // ---- pool + final linear ----
  k_pool_init<<<(G * HDIM + 255) / 256, 256, 0, stream>>>(pooled, G * HDIM);
  k_pool<<<(N + 127) / 128, 128, 0, stream>>>(hcat, batch, pooled, N);
  k_final<<<G, 64, 0, stream>>>(pooled, wlin, blin, (float*)d_out);
}

// Round 4
// 708.415 us; speedup vs baseline: 1.8695x; 1.3048x over previous
//
#include <hip/hip_runtime.h>
#include <math.h>

// ---------------- constants ----------------
constexpr int HDIM = 128;     // hidden width
constexpr int RB   = 136;     // bf16 row stride for hcat/z (272B, 16B aligned)
constexpr float BN_INV = 0.99999500003749980f; // 1/sqrt(1+1e-5)

typedef __attribute__((ext_vector_type(8))) short short8v;   // 8 bf16 (4 VGPR)
typedef __attribute__((ext_vector_type(4))) float float4v;   // MFMA accum

// fp32 -> bf16 (RNE) and back
__device__ __forceinline__ unsigned short f2bf(float f) {
  unsigned u = __float_as_uint(f);
  unsigned r = (u + 0x7FFFu + ((u >> 16) & 1u)) >> 16;
  return (unsigned short)r;
}
__device__ __forceinline__ float b2f(unsigned short h) {
  return __uint_as_float(((unsigned)h) << 16);
}

// monotone float<->uint encoding for atomic max on floats
__device__ __forceinline__ unsigned encf(float f) {
  unsigned u = __float_as_uint(f);
  return (u & 0x80000000u) ? ~u : (u | 0x80000000u);
}
__device__ __forceinline__ float decf(unsigned u) {
  return (u & 0x80000000u) ? __uint_as_float(u ^ 0x80000000u) : __uint_as_float(~u);
}

// ---------------- CSR build ----------------
__global__ void k_hist(const int* __restrict__ ei, int* __restrict__ deg, int E) {
  int e = blockIdx.x * blockDim.x + threadIdx.x;
  if (e < E) atomicAdd(&deg[ei[E + e]], 1);  // dst row
}

__global__ void k_scan_block(const int* __restrict__ deg, int* __restrict__ excl,
                             int* __restrict__ blockSums, int N) {
  __shared__ int s[1024];
  int tid = threadIdx.x;
  int i = blockIdx.x * 1024 + tid;
  int v = (i < N) ? deg[i] : 0;
  s[tid] = v;
  __syncthreads();
  for (int off = 1; off < 1024; off <<= 1) {
    int t = (tid >= off) ? s[tid - off] : 0;
    __syncthreads();
    s[tid] += t;
    __syncthreads();
  }
  if (i < N) excl[i] = s[tid] - v;
  if (tid == 1023) blockSums[blockIdx.x] = s[1023];
}

__global__ void k_scan_sums(int* blockSums, int NB) {
  __shared__ int s[256];
  int tid = threadIdx.x;
  int v = (tid < NB) ? blockSums[tid] : 0;
  s[tid] = v;
  __syncthreads();
  for (int off = 1; off < 256; off <<= 1) {
    int t = (tid >= off) ? s[tid - off] : 0;
    __syncthreads();
    s[tid] += t;
    __syncthreads();
  }
  if (tid < NB) blockSums[tid] = s[tid] - v; // exclusive
}

__global__ void k_scan_add(const int* __restrict__ excl, const int* __restrict__ blockOff,
                           int* __restrict__ rowptr, int N, int E) {
  int i = blockIdx.x * blockDim.x + threadIdx.x;
  if (i < N) rowptr[i] = excl[i] + blockOff[i >> 10];
  if (i == 0) rowptr[N] = E;
}

__global__ void k_fill(const int* __restrict__ ei, const int* __restrict__ rowptr,
                       int* __restrict__ cursor, int* __restrict__ eidx, int E) {
  int e = blockIdx.x * blockDim.x + threadIdx.x;
  if (e >= E) return;
  int s = ei[e];
  int d = ei[E + e];
  int p = atomicAdd(&cursor[d], 1);
  eidx[rowptr[d] + p] = s;
}

// ---------------- feature concat (layer 0), bf16 ----------------
// hcat row: 0..63 = x, 64..65 = pos (layer0 input), 66..127 = 0,
// 128..129 = pos (persistent; after k_mlp writes h to 0..127, [h,pos] = contiguous 130),
// 130..135 = 0 pad.
__global__ void k_concat0(const float* __restrict__ x, const float* __restrict__ pos,
                          unsigned short* __restrict__ hcat, int N) {
  long long idx = (long long)blockIdx.x * blockDim.x + threadIdx.x;
  long long total = (long long)N * RB;
  if (idx >= total) return;
  int r = (int)(idx / RB);
  int c = (int)(idx - (long long)r * RB);
  float v;
  if (c < 64)                   v = x[(size_t)r * 64 + c];
  else if (c < 66)              v = pos[(size_t)r * 2 + (c - 64)];
  else if (c >= 128 && c < 130) v = pos[(size_t)r * 2 + (c - 128)];
  else                          v = 0.0f;
  hcat[idx] = f2bf(v);
}

// ---------------- neighbor max aggregation (bf16):  z = hcat + max_{src->i} hcat[src] ----
// one wave per node; lanes 0..31 = edge stream A, lanes 32..63 = edge stream B.
// lane lc covers bf16 cols lc*4..lc*4+3; lc==0 additionally covers cols 128..131.
__global__ __launch_bounds__(256) void k_agg(
    const unsigned short* __restrict__ hcat, const int* __restrict__ rowptr,
    const int* __restrict__ eidx, unsigned short* __restrict__ z, int din, int N) {
  int wid = (int)((blockIdx.x * 256 + threadIdx.x) >> 6);
  if (wid >= N) return;
  int lane = threadIdx.x & 63;
  int half = lane >> 5;
  int lc = lane & 31;
  int c4 = lc * 4;
  const bool act = c4 < din;                 // din=66 -> lc 0..16, din=130 -> all
  const bool tail = (din > 128) && (lc == 0);

  float m0 = -INFINITY, m1 = -INFINITY, m2 = -INFINITY, m3 = -INFINITY;
  float t0 = -INFINITY, t1 = -INFINITY, t2 = -INFINITY, t3 = -INFINITY;
  int r0 = rowptr[wid], r1 = rowptr[wid + 1];

  int e = r0 + half;
  for (; e + 2 < r1; e += 4) {   // this half processes e and e+2
    int sA = eidx[e], sB = eidx[e + 2];
    const unsigned short* ra = hcat + (size_t)sA * RB;
    const unsigned short* rb = hcat + (size_t)sB * RB;
    if (act) {
      ushort4 va = *(const ushort4*)(ra + c4);
      ushort4 vb = *(const ushort4*)(rb + c4);
      m0 = fmaxf(m0, fmaxf(b2f(va.x), b2f(vb.x)));
      m1 = fmaxf(m1, fmaxf(b2f(va.y), b2f(vb.y)));
      m2 = fmaxf(m2, fmaxf(b2f(va.z), b2f(vb.z)));
      m3 = fmaxf(m3, fmaxf(b2f(va.w), b2f(vb.w)));
    }
    if (tail) {
      ushort4 va = *(const ushort4*)(ra + 128);
      ushort4 vb = *(const ushort4*)(rb + 128);
      t0 = fmaxf(t0, fmaxf(b2f(va.x), b2f(vb.x)));
      t1 = fmaxf(t1, fmaxf(b2f(va.y), b2f(vb.y)));
      t2 = fmaxf(t2, fmaxf(b2f(va.z), b2f(vb.z)));
      t3 = fmaxf(t3, fmaxf(b2f(va.w), b2f(vb.w)));
    }
  }
  for (; e < r1; e += 2) {
    int s = eidx[e];
    const unsigned short* ra = hcat + (size_t)s * RB;
    if (act) {
      ushort4 va = *(const ushort4*)(ra + c4);
      m0 = fmaxf(m0, b2f(va.x));
      m1 = fmaxf(m1, b2f(va.y));
      m2 = fmaxf(m2, b2f(va.z));
      m3 = fmaxf(m3, b2f(va.w));
    }
    if (tail) {
      ushort4 va = *(const ushort4*)(ra + 128);
      t0 = fmaxf(t0, b2f(va.x));
      t1 = fmaxf(t1, b2f(va.y));
      t2 = fmaxf(t2, b2f(va.z));
      t3 = fmaxf(t3, b2f(va.w));
    }
  }

  // combine the two halves
  m0 = fmaxf(m0, __shfl_xor(m0, 32));
  m1 = fmaxf(m1, __shfl_xor(m1, 32));
  m2 = fmaxf(m2, __shfl_xor(m2, 32));
  m3 = fmaxf(m3, __shfl_xor(m3, 32));
  t0 = fmaxf(t0, __shfl_xor(t0, 32));
  t1 = fmaxf(t1, __shfl_xor(t1, 32));
  t2 = fmaxf(t2, __shfl_xor(t2, 32));
  t3 = fmaxf(t3, __shfl_xor(t3, 32));

  const bool none = (r0 == r1);   // empty neighborhood -> agg = 0
  if (half == 0) {
    if (act) {
      const unsigned short* xr = hcat + (size_t)wid * RB + c4;
      ushort4 xv = *(const ushort4*)xr;
      ushort4 o;
      o.x = f2bf(b2f(xv.x) + (none ? 0.0f : m0));
      o.y = f2bf(b2f(xv.y) + (none ? 0.0f : m1));
      o.z = f2bf(b2f(xv.z) + (none ? 0.0f : m2));
      o.w = f2bf(b2f(xv.w) + (none ? 0.0f : m3));
      *(ushort4*)(z + (size_t)wid * RB + c4) = o;
    }
    if (tail) {
      const unsigned short* xr = hcat + (size_t)wid * RB + 128;
      ushort4 xv = *(const ushort4*)xr;
      ushort4 o;
      o.x = f2bf(b2f(xv.x) + (none ? 0.0f : t0));
      o.y = f2bf(b2f(xv.y) + (none ? 0.0f : t1));
      o.z = f2bf(b2f(xv.z) + (none ? 0.0f : t2));
      o.w = f2bf(b2f(xv.w) + (none ? 0.0f : t3));
      *(ushort4*)(z + (size_t)wid * RB + 128) = o;
    }
  }
}

// ---------------- weight prep: W[k][n] fp32 -> Wt[n][kpad] bf16 (zero-padded) ----------------
__global__ void k_prepw(const float* __restrict__ W, int K, int Kpad,
                        unsigned short* __restrict__ Wt) {
  int idx = blockIdx.x * blockDim.x + threadIdx.x;
  if (idx >= 128 * Kpad) return;
  int n = idx / Kpad;
  int k = idx - n * Kpad;
  float v = (k < K) ? W[(size_t)k * 128 + n] : 0.0f;
  Wt[idx] = f2bf(v);
}

// ---------------- fused MFMA MLP: relu(BN(relu(BN(z@W1+b1))@W2+b2)) -> out bf16 ----------------
// Block = 256 threads = 4 waves; block tile = 64 rows x 128 cols; wave w owns rows w*16..+16.
// GEMM1 A-frags read straight from global z (each element read once).
// h1 goes through a per-wave LDS tile (no cross-wave sharing -> no barriers).
// B-frags from pre-transposed bf16 Wt (L2-resident).
__global__ __launch_bounds__(256) void k_mlp(
    const unsigned short* __restrict__ z, int Kpad1, int kc1,
    const unsigned short* __restrict__ Wt1,
    const float* __restrict__ b1, const float* __restrict__ g1, const float* __restrict__ e1,
    const unsigned short* __restrict__ Wt2,
    const float* __restrict__ b2, const float* __restrict__ g2, const float* __restrict__ e2,
    unsigned short* __restrict__ out, int N) {
  const int tid = threadIdx.x;
  const int w = tid >> 6, l = tid & 63;
  const int arow = l & 15;     // A row within 16-row tile; also B/D column offset
  const int grp  = l >> 4;     // k-group (and D row group)
  const int row0 = blockIdx.x * 64 + w * 16;

  __shared__ unsigned short h1[4][16][RB];   // per-wave h1 tile (stride 136 -> bank-friendly)

  int zr = row0 + arow;
  if (zr >= N) zr = N - 1;                   // clamp: keep reads in-bounds; writes guarded
  const unsigned short* zp = z + (size_t)zr * RB + grp * 8;

  float4v acc[8];
#pragma unroll
  for (int i = 0; i < 8; ++i) acc[i] = (float4v){0.f, 0.f, 0.f, 0.f};

  // ---- GEMM1: rows x Kpad1 (zero-padded K) ----
  for (int kc = 0; kc < kc1; ++kc) {
    short8v a = *(const short8v*)(zp + kc * 32);
    const unsigned short* wp = Wt1 + (size_t)arow * Kpad1 + kc * 32 + grp * 8;
#pragma unroll
    for (int nt = 0; nt < 8; ++nt) {
      short8v b = *(const short8v*)(wp + (size_t)(nt * 16) * Kpad1);
      acc[nt] = __builtin_amdgcn_mfma_f32_16x16x32_bf16(a, b, acc[nt], 0, 0, 0);
    }
  }

  // ---- epilogue 1 -> h1 (bf16, LDS) ----
#pragma unroll
  for (int nt = 0; nt < 8; ++nt) {
    int col = nt * 16 + arow;
    float sc = g1[col] * BN_INV;
    float bb = b1[col];
    float be = e1[col];
#pragma unroll
    for (int j = 0; j < 4; ++j) {
      float v = fmaxf(fmaf(acc[nt][j] + bb, sc, be), 0.0f);
      h1[w][grp * 4 + j][col] = f2bf(v);
    }
  }

  // ---- GEMM2: 128 x 128 (same-wave LDS producer/consumer, no barrier) ----
#pragma unroll
  for (int i = 0; i < 8; ++i) acc[i] = (float4v){0.f, 0.f, 0.f, 0.f};
  for (int kc = 0; kc < 4; ++kc) {
    short8v a = *(const short8v*)(&h1[w][arow][kc * 32 + grp * 8]);
    const unsigned short* wp = Wt2 + (size_t)arow * HDIM + kc * 32 + grp * 8;
#pragma unroll
    for (int nt = 0; nt < 8; ++nt) {
      short8v b = *(const short8v*)(wp + (size_t)(nt * 16) * HDIM);
      acc[nt] = __builtin_amdgcn_mfma_f32_16x16x32_bf16(a, b, acc[nt], 0, 0, 0);
    }
  }

  // ---- epilogue 2 -> global bf16 (cols 0..127 of out rows) ----
#pragma unroll
  for (int nt = 0; nt < 8; ++nt) {
    int col = nt * 16 + arow;
    float sc = g2[col] * BN_INV;
    float bb = b2[col];
    float be = e2[col];
#pragma unroll
    for (int j = 0; j < 4; ++j) {
      int gr = row0 + grp * 4 + j;
      if (gr < N) {
        float v = fmaxf(fmaf(acc[nt][j] + bb, sc, be), 0.0f);
        out[(size_t)gr * RB + col] = f2bf(v);
      }
    }
  }
}

// ---------------- global max pool (batch sorted) ----------------
__global__ void k_pool_init(unsigned* pooled, int GH) {
  int i = blockIdx.x * blockDim.x + threadIdx.x;
  if (i < GH) pooled[i] = 0x007FFFFFu;  // enc(-inf)
}

__global__ __launch_bounds__(128) void k_pool(
    const unsigned short* __restrict__ hcat, const int* __restrict__ batch,
    unsigned* __restrict__ pooled, int N) {
  int base = blockIdx.x * 128;
  int c = threadIdx.x;
  int end = min(base + 128, N);
  int curg = -1;
  float m = -INFINITY;
  for (int i = base; i < end; ++i) {
    int g = batch[i];
    if (g != curg) {
      if (curg >= 0) atomicMax(&pooled[curg * HDIM + c], encf(m));
      curg = g;
      m = -INFINITY;
    }
    m = fmaxf(m, b2f(hcat[(size_t)i * RB + c]));
  }
  if (curg >= 0) atomicMax(&pooled[curg * HDIM + c], encf(m));
}

// ---------------- final linear [G,128] @ [128,2] ----------------
__global__ __launch_bounds__(64) void k_final(
    const unsigned* __restrict__ pooled, const float* __restrict__ wlin,
    const float* __restrict__ blin, float* __restrict__ out) {
  int g = blockIdx.x;
  int lane = threadIdx.x;
  float v0 = decf(pooled[g * HDIM + lane]);
  float v1 = decf(pooled[g * HDIM + 64 + lane]);
  if (v0 == -INFINITY) v0 = 0.0f;  // empty graph -> 0
  if (v1 == -INFINITY) v1 = 0.0f;
  float p0 = v0 * wlin[lane * 2 + 0] + v1 * wlin[(64 + lane) * 2 + 0];
  float p1 = v0 * wlin[lane * 2 + 1] + v1 * wlin[(64 + lane) * 2 + 1];
  for (int off = 32; off > 0; off >>= 1) {
    p0 += __shfl_down(p0, off);
    p1 += __shfl_down(p1, off);
  }
  if (lane == 0) {
    out[g * 2 + 0] = p0 + blin[0];
    out[g * 2 + 1] = p1 + blin[1];
  }
}

// ---------------- host launcher ----------------
static inline size_t ws_align(size_t x) { return (x + 511) & ~(size_t)511; }

extern "C" void kernel_launch(void* const* d_in, const int* in_sizes, int n_in,
                              void* d_out, int out_size, void* d_ws, size_t ws_size,
                              hipStream_t stream) {
  const float* x     = (const float*)d_in[0];
  const float* pos   = (const float*)d_in[1];
  const int*   ei    = (const int*)d_in[2];
  const int*   batch = (const int*)d_in[3];
  const float* wlin  = (const float*)d_in[28];
  const float* blin  = (const float*)d_in[29];

  const int N = in_sizes[3];          // batch has N elements
  const int E = in_sizes[2] / 2;
  const int G = out_size / 2;

  // workspace layout
  char* w = (char*)d_ws;
  size_t off = 0;
  auto take = [&](size_t bytes) { void* p = w + off; off += ws_align(bytes); return p; };
  int*            deg    = (int*)take((size_t)N * 4);
  int*            cursor = (int*)take((size_t)N * 4);
  int*            rowptr = (int*)take((size_t)(N + 1) * 4);
  int*            excl   = (int*)take((size_t)N * 4);
  int*            bsums  = (int*)take(4096);
  int*            eidx   = (int*)take((size_t)E * 4);
  unsigned short* hcat   = (unsigned short*)take((size_t)N * RB * 2 + 1024);
  unsigned short* z      = (unsigned short*)take((size_t)N * RB * 2 + 1024);
  unsigned short* Wt1    = (unsigned short*)take((size_t)128 * 160 * 2);
  unsigned short* Wt2    = (unsigned short*)take((size_t)128 * 128 * 2);
  unsigned*       pooled = (unsigned*)take((size_t)G * HDIM * 4);
  (void)ws_size;

  const int NB = (N + 1023) / 1024;

  // ---- build CSR by dst ----
  hipMemsetAsync(deg, 0, (size_t)N * 4, stream);
  k_hist<<<(E + 255) / 256, 256, 0, stream>>>(ei, deg, E);
  k_scan_block<<<NB, 1024, 0, stream>>>(deg, excl, bsums, N);
  k_scan_sums<<<1, 256, 0, stream>>>(bsums, NB);
  k_scan_add<<<(N + 255) / 256, 256, 0, stream>>>(excl, bsums, rowptr, N, E);
  hipMemsetAsync(cursor, 0, (size_t)N * 4, stream);
  k_fill<<<(E + 255) / 256, 256, 0, stream>>>(ei, rowptr, cursor, eidx, E);

  // ---- layer 0 input; z zeroed once (pad cols stay 0 across all layers) ----
  hipMemsetAsync(z, 0, (size_t)N * RB * 2 + 1024, stream);
  {
    long long total = (long long)N * RB;
    k_concat0<<<(int)((total + 255) / 256), 256, 0, stream>>>(x, pos, hcat, N);
  }

  const int din[3]   = {66, 130, 130};
  const int kpad1[3] = {96, 160, 160};   // K zero-padded to 32-multiple
  const int aggBlocks = (N + 3) / 4;     // 4 waves (nodes) per 256-thread block
  const int mlpBlocks = (N + 63) / 64;

  for (int l = 0; l < 3; ++l) {
    const float* w1 = (const float*)d_in[4 + l * 8 + 0];
    const float* b1 = (const float*)d_in[4 + l * 8 + 1];
    const float* g1 = (const float*)d_in[4 + l * 8 + 2];
    const float* e1 = (const float*)d_in[4 + l * 8 + 3];
    const float* w2 = (const float*)d_in[4 + l * 8 + 4];
    const float* b2 = (const float*)d_in[4 + l * 8 + 5];
    const float* g2 = (const float*)d_in[4 + l * 8 + 6];
    const float* e2 = (const float*)d_in[4 + l * 8 + 7];

    const int Kp = kpad1[l];
    k_prepw<<<(128 * Kp + 255) / 256, 256, 0, stream>>>(w1, din[l], Kp, Wt1);
    k_prepw<<<(128 * HDIM + 255) / 256, 256, 0, stream>>>(w2, HDIM, HDIM, Wt2);

    k_agg<<<aggBlocks, 256, 0, stream>>>(hcat, rowptr, eidx, z, din[l], N);
    k_mlp<<<mlpBlocks, 256, 0, stream>>>(z, Kp, Kp / 32, Wt1, b1, g1, e1,
                                         Wt2, b2, g2, e2, hcat, N);
  }

  // ---- pool + final linear ----
  k_pool_init<<<(G * HDIM + 255) / 256, 256, 0, stream>>>(pooled, G * HDIM);
  k_pool<<<(N + 127) / 128, 128, 0, stream>>>(hcat, batch, pooled, N);
  k_final<<<G, 64, 0, stream>>>(pooled, wlin, blin, (float*)d_out);
}

// Round 6
// 654.350 us; speedup vs baseline: 2.0239x; 1.0826x over previous
//
#include <hip/hip_runtime.h>
#include <hip/hip_fp16.h>
#include <math.h>
#include <string.h>

// ---------------- constants ----------------
constexpr int HDIM = 128;     // hidden width
constexpr int RB   = 136;     // fp16 row stride for hcat/z (272B = 17 x 16B)
constexpr float BN_INV = 0.99999500003749980f; // 1/sqrt(1+1e-5)

typedef _Float16 half8v __attribute__((ext_vector_type(8)));  // 8 fp16 (4 VGPR)
typedef __attribute__((ext_vector_type(4))) float float4v;    // MFMA accum

// packed fp16 ops on raw u32 pairs (VOP3P; avoids broken __hmax2 header decl)
__device__ __forceinline__ unsigned pkmax(unsigned a, unsigned b) {
  unsigned r;
  asm volatile("v_pk_max_f16 %0, %1, %2" : "=v"(r) : "v"(a), "v"(b));
  return r;
}
__device__ __forceinline__ unsigned pkadd(unsigned a, unsigned b) {
  unsigned r;
  asm volatile("v_pk_add_f16 %0, %1, %2" : "=v"(r) : "v"(a), "v"(b));
  return r;
}

__device__ __forceinline__ float us2f(unsigned short u) { __half h; memcpy(&h, &u, 2); return __half2float(h); }
__device__ __forceinline__ unsigned short f2us(float f) {
  __half h = __float2half(f); unsigned short u; memcpy(&u, &h, 2); return u;
}

// monotone float<->uint encoding for atomic max on floats
__device__ __forceinline__ unsigned encf(float f) {
  unsigned u = __float_as_uint(f);
  return (u & 0x80000000u) ? ~u : (u | 0x80000000u);
}
__device__ __forceinline__ float decf(unsigned u) {
  return (u & 0x80000000u) ? __uint_as_float(u ^ 0x80000000u) : __uint_as_float(~u);
}

// ================= CSR build (bucketed, write-locality version) =================
__global__ __launch_bounds__(256) void k_hist2(
    const int* __restrict__ ei, int* __restrict__ deg, int* __restrict__ bcnt,
    int E, int shift, int nbkt) {
  __shared__ int hb[256];
  const int tid = threadIdx.x;
  hb[tid] = 0;
  __syncthreads();
  const int base = blockIdx.x * 4096;
#pragma unroll
  for (int k = 0; k < 16; ++k) {
    int e = base + k * 256 + tid;
    if (e < E) {
      int d = ei[E + e];
      atomicAdd(&deg[d], 1);
      atomicAdd(&hb[d >> shift], 1);
    }
  }
  __syncthreads();
  if (tid < nbkt && hb[tid] > 0) atomicAdd(&bcnt[tid], hb[tid]);
}

__global__ void k_scan_block(const int* __restrict__ deg, int* __restrict__ excl,
                             int* __restrict__ blockSums, int N) {
  __shared__ int s[1024];
  int tid = threadIdx.x;
  int i = blockIdx.x * 1024 + tid;
  int v = (i < N) ? deg[i] : 0;
  s[tid] = v;
  __syncthreads();
  for (int off = 1; off < 1024; off <<= 1) {
    int t = (tid >= off) ? s[tid - off] : 0;
    __syncthreads();
    s[tid] += t;
    __syncthreads();
  }
  if (i < N) excl[i] = s[tid] - v;
  if (tid == 1023) blockSums[blockIdx.x] = s[1023];
}

__global__ void k_scan_sums(int* blockSums, int NB) {
  __shared__ int s[256];
  int tid = threadIdx.x;
  int v = (tid < NB) ? blockSums[tid] : 0;
  s[tid] = v;
  __syncthreads();
  for (int off = 1; off < 256; off <<= 1) {
    int t = (tid >= off) ? s[tid - off] : 0;
    __syncthreads();
    s[tid] += t;
    __syncthreads();
  }
  if (tid < NB) blockSums[tid] = s[tid] - v; // exclusive
}

__global__ void k_scan_add(const int* __restrict__ excl, const int* __restrict__ blockOff,
                           int* __restrict__ rowptr, int N, int E) {
  int i = blockIdx.x * blockDim.x + threadIdx.x;
  if (i < N) rowptr[i] = excl[i] + blockOff[i >> 10];
  if (i == 0) rowptr[N] = E;
}

__global__ __launch_bounds__(256) void k_bscan(
    const int* __restrict__ bcnt, int* __restrict__ bbase, int* __restrict__ gcur, int nbkt) {
  __shared__ int s[256];
  int tid = threadIdx.x;
  int v = (tid < nbkt) ? bcnt[tid] : 0;
  s[tid] = v;
  __syncthreads();
  for (int off = 1; off < 256; off <<= 1) {
    int t = (tid >= off) ? s[tid - off] : 0;
    __syncthreads();
    s[tid] += t;
    __syncthreads();
  }
  if (tid < nbkt) {
    int e = s[tid] - v;
    bbase[tid] = e;
    gcur[tid] = e;
  }
}

// phase A: block-local LDS counting-sort of 4096-edge chunks by bucket,
// run-coalesced flush into per-bucket regions of `sorted` (u64 = dst<<32 | src)
__global__ __launch_bounds__(256) void k_bscatter(
    const int* __restrict__ ei, int* __restrict__ gcur,
    unsigned long long* __restrict__ sorted, int E, int shift, int nbkt) {
  __shared__ int hcnt[256];   // per-bucket count, then reused as cursor
  __shared__ int hstart[256]; // exclusive start within chunk
  __shared__ int gbase[256];  // global base for this block's run
  __shared__ unsigned long long sbuf[4096];  // 32 KB

  const int tid = threadIdx.x;
  const int base = blockIdx.x * 4096;
  const int validCount = min(4096, E - base);

  hcnt[tid] = 0;
  __syncthreads();

  int sArr[16], dArr[16];
#pragma unroll
  for (int k = 0; k < 16; ++k) {
    int e = base + k * 256 + tid;
    if (e < E) {
      sArr[k] = ei[e];
      dArr[k] = ei[E + e];
      atomicAdd(&hcnt[dArr[k] >> shift], 1);
    } else {
      sArr[k] = -1; dArr[k] = -1;
    }
  }
  __syncthreads();

  // exclusive scan of hcnt into hstart
  {
    int v = hcnt[tid];
    __shared__ int sc[256];
    sc[tid] = v;
    __syncthreads();
    for (int off = 1; off < 256; off <<= 1) {
      int t = (tid >= off) ? sc[tid - off] : 0;
      __syncthreads();
      sc[tid] += t;
      __syncthreads();
    }
    hstart[tid] = sc[tid] - v;
    if (tid < nbkt && v > 0) gbase[tid] = atomicAdd(&gcur[tid], v);
    hcnt[tid] = sc[tid] - v;  // reset as running cursor
  }
  __syncthreads();

  // scatter into LDS, compacted by bucket
#pragma unroll
  for (int k = 0; k < 16; ++k) {
    if (dArr[k] >= 0) {
      int b = dArr[k] >> shift;
      int p = atomicAdd(&hcnt[b], 1);
      sbuf[p] = ((unsigned long long)(unsigned)dArr[k] << 32) | (unsigned)sArr[k];
    }
  }
  __syncthreads();

  // coalesced copy-out of per-bucket runs
  for (int p = tid; p < validCount; p += 256) {
    unsigned long long v = sbuf[p];
    int b = (int)(v >> 32) >> shift;
    sorted[(size_t)gbase[b] + (p - hstart[b])] = v;
  }
}

// phase B: one block per bucket; scatter src into eidx with L2-local window
__global__ __launch_bounds__(256) void k_fill2(
    const unsigned long long* __restrict__ sorted, const int* __restrict__ bbase,
    const int* __restrict__ bcnt, const int* __restrict__ rowptr,
    int* __restrict__ cursor, int* __restrict__ eidx) {
  const int b = blockIdx.x;
  const int lo = bbase[b], hi = lo + bcnt[b];
  for (int idx = lo + threadIdx.x; idx < hi; idx += 256) {
    unsigned long long v = sorted[idx];
    int d = (int)(v >> 32);
    int s = (int)(v & 0xFFFFFFFFu);
    int p = atomicAdd(&cursor[d], 1);
    eidx[rowptr[d] + p] = s;
  }
}

// ================= feature concat (layer 0), fp16 =================
// hcat row: 0..63 = x, 64..65 = pos (layer0 input), 66..127 = 0,
// 128..129 = pos (persistent), 130..135 = 0 pad.
__global__ void k_concat0(const float* __restrict__ x, const float* __restrict__ pos,
                          unsigned short* __restrict__ hcat, int N) {
  long long idx = (long long)blockIdx.x * blockDim.x + threadIdx.x;
  long long total = (long long)N * RB;
  if (idx >= total) return;
  int r = (int)(idx / RB);
  int c = (int)(idx - (long long)r * RB);
  float v;
  if (c < 64)                   v = x[(size_t)r * 64 + c];
  else if (c < 66)              v = pos[(size_t)r * 2 + (c - 64)];
  else if (c >= 128 && c < 130) v = pos[(size_t)r * 2 + (c - 128)];
  else                          v = 0.0f;
  hcat[idx] = f2us(v);
}

// ================= neighbor max aggregation (fp16, packed v_pk_max_f16) =================
// z = hcat + max_{src->i} hcat[src].  One wave per node; halves process alternate edges.
// Lane lc (0..16) covers fp16 cols lc*8..lc*8+7 (one 16B load per edge).
__global__ __launch_bounds__(256) void k_agg(
    const unsigned short* __restrict__ hcat, const int* __restrict__ rowptr,
    const int* __restrict__ eidx, unsigned short* __restrict__ z, int actA, int N) {
  int wid = (int)((blockIdx.x * 256 + threadIdx.x) >> 6);
  if (wid >= N) return;
  const int lane = threadIdx.x & 63;
  const int half = lane >> 5;
  const int lc = lane & 31;
  const bool act = (lc < actA) | (lc == 16);
  const int cb = lc * 8;   // fp16 col base

  const unsigned NEGINF = 0xFC00FC00u;  // (-inf, -inf) fp16
  unsigned m0 = NEGINF, m1 = NEGINF, m2 = NEGINF, m3 = NEGINF;

  int r0 = rowptr[wid], r1 = rowptr[wid + 1];
  int e = r0 + half;
  for (; e + 2 < r1; e += 4) {   // this half handles e and e+2 (2 gathers in flight)
    int sA = eidx[e], sB = eidx[e + 2];
    if (act) {
      uint4 va = *(const uint4*)(hcat + (size_t)sA * RB + cb);
      uint4 vb = *(const uint4*)(hcat + (size_t)sB * RB + cb);
      m0 = pkmax(m0, pkmax(va.x, vb.x));
      m1 = pkmax(m1, pkmax(va.y, vb.y));
      m2 = pkmax(m2, pkmax(va.z, vb.z));
      m3 = pkmax(m3, pkmax(va.w, vb.w));
    }
  }
  for (; e < r1; e += 2) {
    int s = eidx[e];
    if (act) {
      uint4 va = *(const uint4*)(hcat + (size_t)s * RB + cb);
      m0 = pkmax(m0, va.x);
      m1 = pkmax(m1, va.y);
      m2 = pkmax(m2, va.z);
      m3 = pkmax(m3, va.w);
    }
  }

  // combine the two halves
  m0 = pkmax(m0, (unsigned)__shfl_xor((int)m0, 32));
  m1 = pkmax(m1, (unsigned)__shfl_xor((int)m1, 32));
  m2 = pkmax(m2, (unsigned)__shfl_xor((int)m2, 32));
  m3 = pkmax(m3, (unsigned)__shfl_xor((int)m3, 32));

  if (half == 0 && act) {
    if (r0 == r1) { m0 = 0u; m1 = 0u; m2 = 0u; m3 = 0u; }  // empty neighborhood -> 0
    uint4 sv = *(const uint4*)(hcat + (size_t)wid * RB + cb);
    uint4 o;
    o.x = pkadd(sv.x, m0);
    o.y = pkadd(sv.y, m1);
    o.z = pkadd(sv.z, m2);
    o.w = pkadd(sv.w, m3);
    *(uint4*)(z + (size_t)wid * RB + cb) = o;
  }
}

// ================= weight prep: W[k][n] fp32 -> Wt[n][kpad] fp16 =================
__global__ void k_prepw(const float* __restrict__ W, int K, int Kpad,
                        unsigned short* __restrict__ Wt) {
  int idx = blockIdx.x * blockDim.x + threadIdx.x;
  if (idx >= 128 * Kpad) return;
  int n = idx / Kpad;
  int k = idx - n * Kpad;
  float v = (k < K) ? W[(size_t)k * 128 + n] : 0.0f;
  Wt[idx] = f2us(v);
}

// ================= fused MFMA MLP (fp16 in, f32 accum) =================
// Block = 256 threads = 4 waves; block tile = 64 rows; wave w owns rows w*16..+16.
__global__ __launch_bounds__(256) void k_mlp(
    const unsigned short* __restrict__ z, int Kpad1, int kc1,
    const unsigned short* __restrict__ Wt1,
    const float* __restrict__ b1, const float* __restrict__ g1, const float* __restrict__ e1,
    const unsigned short* __restrict__ Wt2,
    const float* __restrict__ b2, const float* __restrict__ g2, const float* __restrict__ e2,
    unsigned short* __restrict__ out, int N) {
  const int tid = threadIdx.x;
  const int w = tid >> 6, l = tid & 63;
  const int arow = l & 15;     // A row within 16-row tile; also B/D column offset
  const int grp  = l >> 4;     // k-group (and D row group)
  const int row0 = blockIdx.x * 64 + w * 16;

  __shared__ unsigned short h1[4][16][RB];   // per-wave h1 tile

  int zr = row0 + arow;
  if (zr >= N) zr = N - 1;                   // clamp: reads in-bounds; writes guarded
  const unsigned short* zp = z + (size_t)zr * RB + grp * 8;

  float4v acc[8];
#pragma unroll
  for (int i = 0; i < 8; ++i) acc[i] = (float4v){0.f, 0.f, 0.f, 0.f};

  // ---- GEMM1: rows x Kpad1 (zero-padded K; pad weights are 0) ----
  for (int kc = 0; kc < kc1; ++kc) {
    half8v a = *(const half8v*)(zp + kc * 32);
    const unsigned short* wp = Wt1 + (size_t)arow * Kpad1 + kc * 32 + grp * 8;
#pragma unroll
    for (int nt = 0; nt < 8; ++nt) {
      half8v b = *(const half8v*)(wp + (size_t)(nt * 16) * Kpad1);
      acc[nt] = __builtin_amdgcn_mfma_f32_16x16x32_f16(a, b, acc[nt], 0, 0, 0);
    }
  }

  // ---- epilogue 1 -> h1 (fp16, LDS; same-wave producer/consumer) ----
#pragma unroll
  for (int nt = 0; nt < 8; ++nt) {
    int col = nt * 16 + arow;
    float sc = g1[col] * BN_INV;
    float bb = b1[col];
    float be = e1[col];
#pragma unroll
    for (int j = 0; j < 4; ++j) {
      float v = fmaxf(fmaf(acc[nt][j] + bb, sc, be), 0.0f);
      h1[w][grp * 4 + j][col] = f2us(v);
    }
  }

  // ---- GEMM2: 128 x 128 ----
#pragma unroll
  for (int i = 0; i < 8; ++i) acc[i] = (float4v){0.f, 0.f, 0.f, 0.f};
  for (int kc = 0; kc < 4; ++kc) {
    half8v a = *(const half8v*)(&h1[w][arow][kc * 32 + grp * 8]);
    const unsigned short* wp = Wt2 + (size_t)arow * HDIM + kc * 32 + grp * 8;
#pragma unroll
    for (int nt = 0; nt < 8; ++nt) {
      half8v b = *(const half8v*)(wp + (size_t)(nt * 16) * HDIM);
      acc[nt] = __builtin_amdgcn_mfma_f32_16x16x32_f16(a, b, acc[nt], 0, 0, 0);
    }
  }

  // ---- epilogue 2 -> global fp16 (cols 0..127) ----
#pragma unroll
  for (int nt = 0; nt < 8; ++nt) {
    int col = nt * 16 + arow;
    float sc = g2[col] * BN_INV;
    float bb = b2[col];
    float be = e2[col];
#pragma unroll
    for (int j = 0; j < 4; ++j) {
      int gr = row0 + grp * 4 + j;
      if (gr < N) {
        float v = fmaxf(fmaf(acc[nt][j] + bb, sc, be), 0.0f);
        out[(size_t)gr * RB + col] = f2us(v);
      }
    }
  }
}

// ================= global max pool (batch sorted) =================
__global__ void k_pool_init(unsigned* pooled, int GH) {
  int i = blockIdx.x * blockDim.x + threadIdx.x;
  if (i < GH) pooled[i] = 0x007FFFFFu;  // enc(-inf)
}

__global__ __launch_bounds__(128) void k_pool(
    const unsigned short* __restrict__ hcat, const int* __restrict__ batch,
    unsigned* __restrict__ pooled, int N) {
  int base = blockIdx.x * 128;
  int c = threadIdx.x;
  int end = min(base + 128, N);
  int curg = -1;
  float m = -INFINITY;
  for (int i = base; i < end; ++i) {
    int g = batch[i];
    if (g != curg) {
      if (curg >= 0) atomicMax(&pooled[curg * HDIM + c], encf(m));
      curg = g;
      m = -INFINITY;
    }
    m = fmaxf(m, us2f(hcat[(size_t)i * RB + c]));
  }
  if (curg >= 0) atomicMax(&pooled[curg * HDIM + c], encf(m));
}

// ================= final linear [G,128] @ [128,2] =================
__global__ __launch_bounds__(64) void k_final(
    const unsigned* __restrict__ pooled, const float* __restrict__ wlin,
    const float* __restrict__ blin, float* __restrict__ out) {
  int g = blockIdx.x;
  int lane = threadIdx.x;
  float v0 = decf(pooled[g * HDIM + lane]);
  float v1 = decf(pooled[g * HDIM + 64 + lane]);
  if (v0 == -INFINITY) v0 = 0.0f;  // empty graph -> 0
  if (v1 == -INFINITY) v1 = 0.0f;
  float p0 = v0 * wlin[lane * 2 + 0] + v1 * wlin[(64 + lane) * 2 + 0];
  float p1 = v0 * wlin[lane * 2 + 1] + v1 * wlin[(64 + lane) * 2 + 1];
  for (int off = 32; off > 0; off >>= 1) {
    p0 += __shfl_down(p0, off);
    p1 += __shfl_down(p1, off);
  }
  if (lane == 0) {
    out[g * 2 + 0] = p0 + blin[0];
    out[g * 2 + 1] = p1 + blin[1];
  }
}

// ================= host launcher =================
static inline size_t ws_align(size_t x) { return (x + 511) & ~(size_t)511; }

extern "C" void kernel_launch(void* const* d_in, const int* in_sizes, int n_in,
                              void* d_out, int out_size, void* d_ws, size_t ws_size,
                              hipStream_t stream) {
  const float* x     = (const float*)d_in[0];
  const float* pos   = (const float*)d_in[1];
  const int*   ei    = (const int*)d_in[2];
  const int*   batch = (const int*)d_in[3];
  const float* wlin  = (const float*)d_in[28];
  const float* blin  = (const float*)d_in[29];

  const int N = in_sizes[3];          // batch has N elements
  const int E = in_sizes[2] / 2;
  const int G = out_size / 2;

  // bucket geometry: <=256 buckets of 2^shift nodes
  int shift = 9;
  while ((((N - 1) >> shift) + 1) > 256) ++shift;
  const int nbkt = ((N - 1) >> shift) + 1;

  // workspace layout
  char* w = (char*)d_ws;
  size_t off = 0;
  auto take = [&](size_t bytes) { void* p = w + off; off += ws_align(bytes); return p; };
  int*            deg    = (int*)take((size_t)N * 4);
  int*            cursor = (int*)take((size_t)N * 4);
  int*            rowptr = (int*)take((size_t)(N + 1) * 4);
  int*            excl   = (int*)take((size_t)N * 4);
  int*            bsums  = (int*)take(4096);
  int*            bcnt   = (int*)take(1024);
  int*            bbase  = (int*)take(1024);
  int*            gcur   = (int*)take(1024);
  int*            eidx   = (int*)take((size_t)E * 4);
  unsigned long long* sorted = (unsigned long long*)take((size_t)E * 8);
  unsigned short* hcat   = (unsigned short*)take((size_t)N * RB * 2 + 1024);
  unsigned short* z      = (unsigned short*)take((size_t)N * RB * 2 + 1024);
  unsigned short* Wt1    = (unsigned short*)take((size_t)128 * 160 * 2);
  unsigned short* Wt2    = (unsigned short*)take((size_t)128 * 128 * 2);
  unsigned*       pooled = (unsigned*)take((size_t)G * HDIM * 4);
  (void)ws_size;

  const int NB = (N + 1023) / 1024;
  const int chunks = (E + 4095) / 4096;

  // ---- build CSR by dst (bucketed two-phase, write-locality) ----
  hipMemsetAsync(deg, 0, (size_t)N * 4, stream);
  hipMemsetAsync(bcnt, 0, 1024, stream);
  k_hist2<<<chunks, 256, 0, stream>>>(ei, deg, bcnt, E, shift, nbkt);
  k_scan_block<<<NB, 1024, 0, stream>>>(deg, excl, bsums, N);
  k_scan_sums<<<1, 256, 0, stream>>>(bsums, NB);
  k_scan_add<<<(N + 255) / 256, 256, 0, stream>>>(excl, bsums, rowptr, N, E);
  k_bscan<<<1, 256, 0, stream>>>(bcnt, bbase, gcur, nbkt);
  k_bscatter<<<chunks, 256, 0, stream>>>(ei, gcur, sorted, E, shift, nbkt);
  hipMemsetAsync(cursor, 0, (size_t)N * 4, stream);
  k_fill2<<<nbkt, 256, 0, stream>>>(sorted, bbase, bcnt, rowptr, cursor, eidx);

  // ---- layer 0 input; z zeroed once (pad cols stay valid across layers) ----
  hipMemsetAsync(z, 0, (size_t)N * RB * 2 + 1024, stream);
  {
    long long total = (long long)N * RB;
    k_concat0<<<(int)((total + 255) / 256), 256, 0, stream>>>(x, pos, hcat, N);
  }

  const int din[3]   = {66, 130, 130};
  const int kpad1[3] = {96, 160, 160};   // K zero-padded to 32-multiple
  const int actA[3]  = {9, 17, 17};      // active 8-col lane groups in k_agg
  const int aggBlocks = (N + 3) / 4;     // 4 waves (nodes) per 256-thread block
  const int mlpBlocks = (N + 63) / 64;

  for (int l = 0; l < 3; ++l) {
    const float* w1 = (const float*)d_in[4 + l * 8 + 0];
    const float* b1 = (const float*)d_in[4 + l * 8 + 1];
    const float* g1 = (const float*)d_in[4 + l * 8 + 2];
    const float* e1 = (const float*)d_in[4 + l * 8 + 3];
    const float* w2 = (const float*)d_in[4 + l * 8 + 4];
    const float* b2 = (const float*)d_in[4 + l * 8 + 5];
    const float* g2 = (const float*)d_in[4 + l * 8 + 6];
    const float* e2 = (const float*)d_in[4 + l * 8 + 7];

    const int Kp = kpad1[l];
    k_prepw<<<(128 * Kp + 255) / 256, 256, 0, stream>>>(w1, din[l], Kp, Wt1);
    k_prepw<<<(128 * HDIM + 255) / 256, 256, 0, stream>>>(w2, HDIM, HDIM, Wt2);

    k_agg<<<aggBlocks, 256, 0, stream>>>(hcat, rowptr, eidx, z, actA[l], N);
    k_mlp<<<mlpBlocks, 256, 0, stream>>>(z, Kp, Kp / 32, Wt1, b1, g1, e1,
                                         Wt2, b2, g2, e2, hcat, N);
  }

  // ---- pool + final linear ----
  k_pool_init<<<(G * HDIM + 255) / 256, 256, 0, stream>>>(pooled, G * HDIM);
  k_pool<<<(N + 127) / 128, 128, 0, stream>>>(hcat, batch, pooled, N);
  k_final<<<G, 64, 0, stream>>>(pooled, wlin, blin, (float*)d_out);
}